// Round 7
// baseline (172.297 us; speedup 1.0000x reference)
//
#include <hip/hip_runtime.h>
#include <hip/hip_bf16.h>

// SelfAttention B=4 S=2048 D=1024:
//   out = softmax((xWq^T+bq)(xWk^T+bk)^T / 32) (xWv^T+bv)
// QKV: proven 4-wave 128x128 GEMM (894 TF, 1536 blocks = 2 exact rounds at
// 3 blocks/CU). QK^T/PV: NEW 8-wave 128x128 GEMM with LDS padded to 56 KB to
// pin 2 blocks/CU -> power-of-2 capacity (512) so 1024/512-block grids fill
// exactly (fixes measured 67% residency). Same 0-conflict chunk-XOR swizzle,
// global_load_lds width-16, 16x16x32 MFMA everywhere.
// ws: xb[8192*1024]bf16 | wq,wk,wv[1024^2]bf16 contig | qb,kb[8192*1024]bf16 |
//     vtb[4][1024][2048]bf16 | sc[nb][2048^2]bf16 (softmax in-place)

typedef __hip_bfloat16 bf16;
typedef __attribute__((ext_vector_type(8))) short bf16x8;
typedef __attribute__((ext_vector_type(4))) float f32x4;
typedef __attribute__((ext_vector_type(4))) short short4v;

__device__ __forceinline__ void gload16(const bf16* g, bf16* l) {
  __builtin_amdgcn_global_load_lds(
      (const __attribute__((address_space(1))) void*)g,
      (__attribute__((address_space(3))) void*)l, 16, 0, 0);
}

__global__ __launch_bounds__(256)
void cast_f32_to_bf16(const float* __restrict__ in, bf16* __restrict__ out) {
  long i = ((long)blockIdx.x * blockDim.x + threadIdx.x) * 4;
  float4 f = *(const float4*)(in + i);
  bf16 tmp[4];
  tmp[0] = __float2bfloat16(f.x);
  tmp[1] = __float2bfloat16(f.y);
  tmp[2] = __float2bfloat16(f.z);
  tmp[3] = __float2bfloat16(f.w);
  *(short4v*)(out + i) = *(short4v*)tmp;
}

__global__ __launch_bounds__(256)
void cast3_f32_to_bf16(const float* __restrict__ w0, const float* __restrict__ w1,
                       const float* __restrict__ w2, bf16* __restrict__ out) {
  const float* src = (blockIdx.y == 0) ? w0 : (blockIdx.y == 1) ? w1 : w2;
  long i = ((long)blockIdx.x * blockDim.x + threadIdx.x) * 4;
  float4 f = *(const float4*)(src + i);
  bf16 tmp[4];
  tmp[0] = __float2bfloat16(f.x);
  tmp[1] = __float2bfloat16(f.y);
  tmp[2] = __float2bfloat16(f.z);
  tmp[3] = __float2bfloat16(f.w);
  *(short4v*)(out + (long)blockIdx.y * 1024 * 1024 + i) = *(short4v*)tmp;
}

// ===== QKV projection kernel (proven): 128x128 tile, 4 waves, BK=64 =====
// LDS 32 KB -> 3 blocks/CU; grid 1536 = 2 exact rounds.
// OMODE 3 only: z=0,1: bf16 [8192][1024]+bias (Q,K); z=2: V^T into vtb.
template<int OMODE>
__global__ __launch_bounds__(256, 3)
void gemm_bt(const bf16* __restrict__ A, const bf16* __restrict__ Bt,
             const float* __restrict__ b0, const float* __restrict__ b1,
             const float* __restrict__ b2, void* __restrict__ Cout,
             int K, int lda, int ldb, int ldc, float scale,
             long sA, long sB, long sC)
{
  __shared__ __align__(16) bf16 As[128 * 64];
  __shared__ __align__(16) bf16 Bs[128 * 64];
  const int tid = threadIdx.x;
  const int z = blockIdx.z;
  const bf16* Ab = A + (long)z * sA;
  const bf16* Bb = Bt + (long)z * sB;
  const long bm = (long)blockIdx.x * 128;
  const long bn = (long)blockIdx.y * 128;
  const int wid = tid >> 6;
  const int lane = tid & 63;
  const int wr = (wid >> 1) * 64;
  const int wc = (wid & 1) * 64;
  const int l15 = lane & 15;
  const int kg = lane >> 4;

  f32x4 acc[4][4];
#pragma unroll
  for (int m = 0; m < 4; ++m)
#pragma unroll
    for (int n = 0; n < 4; ++n)
      acc[m][n] = (f32x4){0.f, 0.f, 0.f, 0.f};

  for (int k0 = 0; k0 < K; k0 += 64) {
#pragma unroll
    for (int i = 0; i < 4; ++i) {
      const int c = (i << 8) + tid;
      const int r = c >> 3;
      const int j = (c & 7) ^ (r & 7);
      const int ldsch = (i << 8) + (wid << 6);
      gload16(Ab + (long)(bm + r) * lda + k0 + (j << 3), As + ldsch * 8);
      gload16(Bb + (long)(bn + r) * ldb + k0 + (j << 3), Bs + ldsch * 8);
    }
    __syncthreads();
#pragma unroll
    for (int kk = 0; kk < 2; ++kk) {
      bf16x8 af[4], bfv[4];
#pragma unroll
      for (int m = 0; m < 4; ++m) {
        const int row_l = wr + (m << 4) + l15;
        const int js = ((kk << 2) + kg) ^ (row_l & 7);
        af[m] = *(const bf16x8*)&As[(row_l << 6) + (js << 3)];
      }
#pragma unroll
      for (int n = 0; n < 4; ++n) {
        const int row_l = wc + (n << 4) + l15;
        const int js = ((kk << 2) + kg) ^ (row_l & 7);
        bfv[n] = *(const bf16x8*)&Bs[(row_l << 6) + (js << 3)];
      }
#pragma unroll
      for (int m = 0; m < 4; ++m)
#pragma unroll
        for (int n = 0; n < 4; ++n)
          acc[m][n] = __builtin_amdgcn_mfma_f32_16x16x32_bf16(
              af[m], bfv[n], acc[m][n], 0, 0, 0);
    }
    __syncthreads();
  }

#pragma unroll
  for (int m = 0; m < 4; ++m) {
    const long row0 = bm + wr + (m << 4) + (kg << 2);
#pragma unroll
    for (int n = 0; n < 4; ++n) {
      const long col = bn + wc + (n << 4) + l15;
      const float* bias = (z == 0) ? b0 : (z == 1) ? b1 : b2;
      const float bias_v = bias[col];
      if (z < 2) {
        bf16* C = (bf16*)Cout + (long)z * 8192 * 1024;
#pragma unroll
        for (int rr = 0; rr < 4; ++rr)
          C[(row0 + rr) * 1024 + col] =
              __float2bfloat16(acc[m][n][rr] + bias_v);
      } else {
        bf16* C = (bf16*)Cout + 2L * 8192 * 1024;  // vtb
        const long bb = row0 >> 11;
        const long s0 = row0 & 2047;  // multiple of 4 -> 8B-aligned
        bf16 tmp[4];
#pragma unroll
        for (int rr = 0; rr < 4; ++rr)
          tmp[rr] = __float2bfloat16(acc[m][n][rr] + bias_v);
        *(short4v*)&C[(bb * 1024 + col) * 2048 + s0] = *(short4v*)tmp;
      }
    }
  }
}

// ===== attention GEMM kernel: 128x128 tile, 8 waves (2Mx4N), BK=64 =====
// Wave-tile 64x32 = 4m x 2n frags of 16x16. LDS padded to 56 KB -> exactly
// 2 blocks/CU (16 waves/CU), so 1024/512-block grids fill with no remainder.
// Same chunk-XOR swizzle (2-way on bank quads = free).
// OMODE 0: fp32 C = scale*(A Bt^T) + z*sC    [PV -> out]
// OMODE 1: bf16 C = scale*(A Bt^T) + z*sC    [QK^T -> scores]
template<int OMODE>
__global__ __launch_bounds__(512, 4)
void gemm8w(const bf16* __restrict__ A, const bf16* __restrict__ Bt,
            void* __restrict__ Cout, int K, int lda, int ldb, int ldc,
            float scale, long sA, long sB, long sC)
{
  // 16 KB + 12 KB pad each -> 56 KB total: floor(160/56) = 2 blocks/CU.
  __shared__ __align__(16) bf16 As[128 * 64 + 6144];
  __shared__ __align__(16) bf16 Bs[128 * 64 + 6144];
  const int tid = threadIdx.x;
  const int z = blockIdx.z;
  const bf16* Ab = A + (long)z * sA;
  const bf16* Bb = Bt + (long)z * sB;
  const long bm = (long)blockIdx.x * 128;
  const long bn = (long)blockIdx.y * 128;
  const int wid = tid >> 6;
  const int lane = tid & 63;
  const int wr = (wid >> 2) * 64;   // 2 wave-rows
  const int wc = (wid & 3) * 32;    // 4 wave-cols
  const int l15 = lane & 15;
  const int kg = lane >> 4;

  f32x4 acc[4][2];
#pragma unroll
  for (int m = 0; m < 4; ++m)
#pragma unroll
    for (int n = 0; n < 2; ++n)
      acc[m][n] = (f32x4){0.f, 0.f, 0.f, 0.f};

  for (int k0 = 0; k0 < K; k0 += 64) {
    // stage 128x64 of A and Bt: 1024 chunks / 512 thr = 2 each per array
#pragma unroll
    for (int i = 0; i < 2; ++i) {
      const int c = (i << 9) + tid;
      const int r = c >> 3;
      const int j = (c & 7) ^ (r & 7);
      const int ldsch = (i << 9) + (wid << 6);  // wave-uniform chunk base
      gload16(Ab + (long)(bm + r) * lda + k0 + (j << 3), As + ldsch * 8);
      gload16(Bb + (long)(bn + r) * ldb + k0 + (j << 3), Bs + ldsch * 8);
    }
    __syncthreads();
#pragma unroll
    for (int kk = 0; kk < 2; ++kk) {
      bf16x8 af[4], bfv[2];
#pragma unroll
      for (int m = 0; m < 4; ++m) {
        const int row_l = wr + (m << 4) + l15;
        const int js = ((kk << 2) + kg) ^ (row_l & 7);
        af[m] = *(const bf16x8*)&As[(row_l << 6) + (js << 3)];
      }
#pragma unroll
      for (int n = 0; n < 2; ++n) {
        const int row_l = wc + (n << 4) + l15;
        const int js = ((kk << 2) + kg) ^ (row_l & 7);
        bfv[n] = *(const bf16x8*)&Bs[(row_l << 6) + (js << 3)];
      }
#pragma unroll
      for (int m = 0; m < 4; ++m)
#pragma unroll
        for (int n = 0; n < 2; ++n)
          acc[m][n] = __builtin_amdgcn_mfma_f32_16x16x32_bf16(
              af[m], bfv[n], acc[m][n], 0, 0, 0);
    }
    __syncthreads();
  }

  // C/D frag layout (m89): row = kg*4 + rr, col = l15
#pragma unroll
  for (int m = 0; m < 4; ++m) {
    const long row0 = bm + wr + (m << 4) + (kg << 2);
#pragma unroll
    for (int n = 0; n < 2; ++n) {
      const long col = bn + wc + (n << 4) + l15;
      if constexpr (OMODE == 0) {
        float* C = (float*)Cout + (long)z * sC;
#pragma unroll
        for (int rr = 0; rr < 4; ++rr)
          C[(row0 + rr) * ldc + col] = acc[m][n][rr] * scale;
      } else {
        bf16* C = (bf16*)Cout + (long)z * sC;
#pragma unroll
        for (int rr = 0; rr < 4; ++rr)
          C[(row0 + rr) * ldc + col] = __float2bfloat16(acc[m][n][rr] * scale);
      }
    }
  }
}

// softmax over bf16 score row [2048], in-place.
__global__ __launch_bounds__(256)
void softmax_bf16(bf16* __restrict__ S) {
  bf16* row = S + (size_t)blockIdx.x * 2048;
  const int tid = threadIdx.x;
  __shared__ float redA[4], redB[4];
  bf16x8 in = *(const bf16x8*)(row + (tid << 3));
  float v[8];
  float mx = -1e30f;
#pragma unroll
  for (int i = 0; i < 8; ++i) {
    v[i] = __bfloat162float(((const bf16*)&in)[i]);
    mx = fmaxf(mx, v[i]);
  }
#pragma unroll
  for (int o = 32; o; o >>= 1) mx = fmaxf(mx, __shfl_xor(mx, o));
  if ((tid & 63) == 0) redA[tid >> 6] = mx;
  __syncthreads();
  mx = fmaxf(fmaxf(redA[0], redA[1]), fmaxf(redA[2], redA[3]));
  float sum = 0.f;
#pragma unroll
  for (int i = 0; i < 8; ++i) {
    v[i] = __expf(v[i] - mx);
    sum += v[i];
  }
#pragma unroll
  for (int o = 32; o; o >>= 1) sum += __shfl_xor(sum, o);
  if ((tid & 63) == 0) redB[tid >> 6] = sum;
  __syncthreads();
  sum = redB[0] + redB[1] + redB[2] + redB[3];
  const float inv = 1.f / sum;
  bf16 tmp[8];
#pragma unroll
  for (int i = 0; i < 8; ++i) tmp[i] = __float2bfloat16(v[i] * inv);
  *(bf16x8*)(row + (tid << 3)) = *(bf16x8*)tmp;
}

extern "C" void kernel_launch(void* const* d_in, const int* in_sizes, int n_in,
                              void* d_out, int out_size, void* d_ws, size_t ws_size,
                              hipStream_t stream) {
  const float* x  = (const float*)d_in[0];
  const float* Wq = (const float*)d_in[1];
  const float* bq = (const float*)d_in[2];
  const float* Wk = (const float*)d_in[3];
  const float* bk = (const float*)d_in[4];
  const float* Wv = (const float*)d_in[5];
  const float* bv = (const float*)d_in[6];
  float* out = (float*)d_out;

  const int B = 4, S = 2048, D = 1024;
  const int M = B * S;  // 8192

  bf16* xb  = (bf16*)d_ws;
  bf16* wqb = xb + (size_t)M * D;       // wq,wk,wv contiguous
  bf16* qb  = wqb + 3 * (size_t)D * D;
  bf16* kb  = qb + (size_t)M * D;
  bf16* vtb = kb + (size_t)M * D;
  bf16* sc  = vtb + (size_t)M * D;      // bf16 scores, nb batches

  size_t avail = ws_size - ((size_t)((char*)sc - (char*)d_ws));
  int nb = (int)(avail / ((size_t)S * S * 2));
  if (nb > B) nb = B;
  if (nb < 1) nb = 1;

  // casts
  cast_f32_to_bf16<<<dim3(M * D / 1024), 256, 0, stream>>>(x, xb);
  cast3_f32_to_bf16<<<dim3(D * D / 1024, 3), 256, 0, stream>>>(Wq, Wk, Wv, wqb);

  // fused QKV projection (z: 0=Q, 1=K, 2=V^T), grid 64x8x3 = 1536 blocks
  gemm_bt<3><<<dim3(M / 128, D / 128, 3), 256, 0, stream>>>(
      xb, wqb, bq, bk, bv, qb, D, D, D, D, 1.f, 0, (long)D * D, 0);

  const float iscale = 1.0f / 32.0f;  // 1/sqrt(1024)
  for (int g = 0; g < B; g += nb) {
    const int gn = (g + nb <= B) ? nb : (B - g);
    // QK^T -> bf16 scores: 1024 blocks = 2 exact rounds at 2/CU
    gemm8w<1><<<dim3(S / 128, S / 128, gn), 512, 0, stream>>>(
        qb + (size_t)g * S * D, kb + (size_t)g * S * D,
        sc, D, D, D, S, iscale, (long)S * D, (long)S * D, (long)S * S);
    softmax_bf16<<<dim3(gn * S), 256, 0, stream>>>(sc);
    // PV: 512 blocks = 1 exact round at 2/CU
    gemm8w<0><<<dim3(S / 128, D / 128, gn), 512, 0, stream>>>(
        sc, vtb + (size_t)g * D * S,
        out + (size_t)g * S * D, S, S, S, D, 1.f,
        (long)S * S, (long)D * S, (long)S * D);
  }
}